// Round 1
// baseline (113.464 us; speedup 1.0000x reference)
//
#include <hip/hip_runtime.h>
#include <hip/hip_bf16.h>

typedef __attribute__((ext_vector_type(8))) __bf16 bf16x8;
typedef __attribute__((ext_vector_type(4))) float f32x4;
typedef __attribute__((ext_vector_type(8))) unsigned short u16x8;

#define DEVI __device__ __forceinline__
#define MFMA(a,b,c) __builtin_amdgcn_mfma_f32_16x16x32_bf16((a),(b),(c),0,0,0)
#define EXP2F(x) __builtin_exp2f(x)
#define LOG2F(x) __builtin_log2f(x)

DEVI unsigned short f2bf(float f){ __bf16 h = (__bf16)f; return __builtin_bit_cast(unsigned short, h); }
DEVI float bf2f(unsigned short u){ unsigned int x = ((unsigned int)u) << 16; return __builtin_bit_cast(float, x); }
DEVI bf16x8 ld_bf8(const void* p){ u16x8 u = *(const u16x8*)p; return __builtin_bit_cast(bf16x8, u); }
DEVI f32x4 splat4(float x){ f32x4 v = {x,x,x,x}; return v; }
DEVI f32x4 vmax4(f32x4 a, f32x4 b){
  f32x4 r;
  #pragma unroll
  for (int i=0;i<4;++i) r[i]=fmaxf(a[i],b[i]);
  return r;
}
DEVI void gload_lds16(const void* g, void* l){
  void* g2 = const_cast<void*>(g);
  __builtin_amdgcn_global_load_lds((__attribute__((address_space(1))) void*)g2,
                                   (__attribute__((address_space(3))) void*)l, 16, 0, 0);
}

// schedule table: 30 chunks per segment, heavy-first. qb | t0<<8 | ntiles<<16 | slot<<24 (64-row tile units)
__device__ const unsigned int SCHED[30] = {
  0x100C000Bu, 0x110C0C0Bu, 0x050C0005u, 0x1C0B0A0Fu, 0x1D0B150Fu,
  0x0E0B000Au, 0x0F0B0B0Au, 0x1B0A000Fu, 0x180A000Eu, 0x190A0A0Eu,
  0x1A0A140Eu, 0x170A120Du, 0x0C0A0009u, 0x0D0A0A09u, 0x040A0004u,
  0x1509000Du, 0x1609090Du, 0x1309080Cu, 0x1409110Cu, 0x0A090008u,
  0x0B090908u, 0x1208000Cu, 0x08080007u, 0x09080807u, 0x03080003u,
  0x06070006u, 0x07070706u, 0x02060002u, 0x01040001u, 0x00020000u
};
// canonical chunk-base per qb (prefix of nchunks {1x6, 2x6, 3x4})
__device__ const int CB[16] = {0,1,2,3,4,5,6,8,10,12,14,16,18,21,24,27};

// ---------------- prep: transpose weights to [mat][col][k] bf16; fold 1/(sqrt(c)*ln2) into Wq (base-2 softmax)
__global__ __launch_bounds__(256) void k_prep(const float* __restrict__ Wq, const float* __restrict__ Wk,
                                              const float* __restrict__ Wv, const float* __restrict__ Wo,
                                              unsigned short* __restrict__ wT){
  int i = blockIdx.x*256 + threadIdx.x;              // 0..65535
  int mat = i >> 14, col = (i >> 7) & 127, k = i & 127;
  const float* W = (mat==0)?Wq:(mat==1)?Wk:(mat==2)?Wv:Wo;
  float v = W[k*128 + col];
  if (mat == 0) v *= 0.12754245006257017f;           // 1/(sqrt(128)*ln2)
  wT[i] = f2bf(v);
}

// ---------------- QKV projection + in-kernel V transpose to branch-local, kv-permuted V^T arrays.
// Within each 32-rank block, rank kv is stored at position p = ((kv&15)>>2)*8 + ((kv>>4)&1)*4 + (kv&3),
// so the PV B-operand k-slot (hi,e) holds kv = (e>=4)*16 + hi*4 + (e&3)  ->  P pack is lane-local.
__global__ __launch_bounds__(256) void k_qkv(const float* __restrict__ x, const unsigned short* __restrict__ wT,
                                             unsigned short* __restrict__ Qo, unsigned short* __restrict__ Ko,
                                             unsigned short* __restrict__ VT0, unsigned short* __restrict__ VT1,
                                             unsigned short* __restrict__ VT2){
  __shared__ unsigned short Tl[128*130];             // [token 0..127][d 0..127], row stride 130
  const int tid=threadIdx.x, lane=tid&63, wid=tid>>6, ll=lane&15, hi=lane>>4;
  const int row0g = blockIdx.x*128;
  const long row0 = (long)row0g + wid*32;
  bf16x8 a[2][4];
  #pragma unroll
  for (int mt=0;mt<2;++mt){
    const float* xr = x + (row0 + mt*16 + ll)*128 + hi*8;
    #pragma unroll
    for (int ks=0;ks<4;++ks){
      f32x4 f0 = *(const f32x4*)(const void*)(xr + ks*32);
      f32x4 f1 = *(const f32x4*)(const void*)(xr + ks*32 + 4);
      u16x8 u;
      #pragma unroll
      for (int j=0;j<4;++j){ u[j]=f2bf(f0[j]); u[j+4]=f2bf(f1[j]); }
      a[mt][ks] = __builtin_bit_cast(bf16x8, u);
    }
  }
  #pragma unroll
  for (int m3=0;m3<3;++m3){
    const unsigned short* wp = wT + m3*16384 + ll*128 + hi*8;
    #pragma unroll
    for (int nt=0;nt<8;++nt){
      f32x4 acc0=splat4(0.f), acc1=splat4(0.f);
      #pragma unroll
      for (int ks=0;ks<4;++ks){
        bf16x8 b = ld_bf8(wp + nt*2048 + ks*32);
        acc0 = MFMA(a[0][ks], b, acc0);
        acc1 = MFMA(a[1][ks], b, acc1);
      }
      if (m3 < 2){
        unsigned short* outp = (m3==0)?Qo:Ko;
        #pragma unroll
        for (int r=0;r<4;++r){
          outp[(row0 + hi*4 + r)*128 + nt*16 + ll]      = f2bf(acc0[r]);
          outp[(row0 + 16 + hi*4 + r)*128 + nt*16 + ll] = f2bf(acc1[r]);
        }
      } else {
        #pragma unroll
        for (int r=0;r<4;++r){
          Tl[(wid*32 + hi*4 + r)*130 + nt*16 + ll]      = f2bf(acc0[r]);
          Tl[(wid*32 + 16 + hi*4 + r)*130 + nt*16 + ll] = f2bf(acc1[r]);
        }
      }
    }
  }
  __syncthreads();
  // write-out V^T rows, kv-permuted within 32-rank blocks (rank pair 2*lane,2*lane+1 stays adjacent:
  // for even rank r&3 in {0,2}, p(kv+1)=p(kv)+1)
  int tk = 2*lane;
  int pp0 = (tk>>5)*32 + ((tk>>4)&1)*4 + ((tk&15)>>2)*8 + (tk&3);
  #pragma unroll 4
  for (int p=0;p<32;++p){
    int d = wid*32 + p;
    unsigned int w0 = (unsigned int)Tl[(2*lane)*130 + d] | ((unsigned int)Tl[(2*lane+1)*130 + d] << 16);
    *(unsigned int*)(VT0 + (long)d*32768 + row0g + pp0) = w0;
    if (lane < 32){
      unsigned int w1 = (unsigned int)Tl[(4*lane)*130 + d] | ((unsigned int)Tl[(4*lane+2)*130 + d] << 16);
      *(unsigned int*)(VT1 + (long)d*16384 + (row0g>>1) + pp0) = w1;
    }
    if (lane < 16){
      unsigned int w2 = (unsigned int)Tl[(8*lane)*130 + d] | ((unsigned int)Tl[(8*lane+4)*130 + d] << 16);
      *(unsigned int*)(VT2 + (long)d*8192 + (row0g>>2) + pp0) = w2;
    }
  }
}

// ---------------- flash attention: KV tile 32, DMA-staged K+V, ring-3 buffers.
// Per iteration: counted vmcnt + FULL lgkm drain (own ds_reads serviced) -> s_barrier -> compute(it) -> STAGE(it+2).
// Race-free: lgkmcnt(0) before the barrier guarantees every wave's slot-((it-1)%3) LDS reads are SERVICED
// before it signals barrier #it; STAGE(it+2) (which overwrites that slot) can only issue after the barrier
// releases. Without the lgkm drain the compiler may sink the consuming register-only MFMAs (and their
// lgkm waits) past the raw barrier, leaving ds_reads outstanding when the DMA overwrite lands (rare race,
// seen as post-timing divergence). Zero-shuffle PV via kv-permuted V^T.
__global__ __launch_bounds__(256,3) void k_attn(
    const unsigned short* __restrict__ Qg, const unsigned short* __restrict__ Kg,
    const unsigned short* __restrict__ VT0, const unsigned short* __restrict__ VT1,
    const unsigned short* __restrict__ VT2,
    unsigned short* __restrict__ OP, float* __restrict__ LP){
  __shared__ unsigned char smem[49152];
  // K ring: 3 x 8KB at smem + s*8192 ; V ring: 3 x 8KB at smem + 24576 + s*8192

  const int tid=threadIdx.x, lane=tid&63, wid=tid>>6, ll=lane&15, hi=lane>>4;

  int j = blockIdx.x;
  int sid = j % 28;
  int r = j / 28;
  unsigned int e = SCHED[r];
  int qb   = (int)(e & 255u);
  int t032 = (int)((e >> 8) & 255u) * 2;
  int n32  = (int)((e >> 16) & 255u) * 2;
  int slot = (int)(e >> 24);
  int br, bb, seg;
  if (sid < 16){ br=0; bb=sid>>2; seg=sid&3; }
  else if (sid < 24){ br=1; bb=(sid-16)>>1; seg=(sid-16)&1; }
  else { br=2; bb=sid-24; seg=0; }
  const int rstr = 1 << br;
  const long g0 = (long)bb*8192 + (long)seg*(2048 << br);
  const int P = sid*30 + slot;
  const unsigned short* VTb = (br==0)?VT0:(br==1)?VT1:VT2;
  const int NC = 32768 >> br;
  const int rb0 = (int)(g0 >> br);

  const int qrow_w = qb*128 + wid*32;

  bf16x8 aq[2][4];
  #pragma unroll
  for (int mt=0;mt<2;++mt){
    long gq = g0 + (long)rstr*(qrow_w + mt*16 + ll);
    const unsigned short* qp = Qg + gq*128 + hi*8;
    #pragma unroll
    for (int ks=0;ks<4;++ks) aq[mt][ks] = ld_bf8(qp + ks*32);
  }

  f32x4 o[2][8];
  #pragma unroll
  for (int mt=0;mt<2;++mt){
    #pragma unroll
    for (int dt=0;dt<8;++dt) o[mt][dt]=splat4(0.f);
  }
  float mrun[2], lrun[2];
  mrun[0]=mrun[1]=-1e30f; lrun[0]=lrun[1]=0.f;

  // stage tile (32 rows) kt into ring slot b: 2 K-gloads + 2 V-gloads per wave (4 total)
#define STAGE(ktv, bslot)                                                              \
  {                                                                                    \
    unsigned char* Kb = smem + (bslot)*8192;                                           \
    unsigned char* Vb = smem + 24576 + (bslot)*8192;                                   \
    _Pragma("unroll")                                                                  \
    for (int i_=0;i_<2;++i_){                                                          \
      int rbase = wid*8 + i_*4;                                                        \
      int row = rbase + hi;                                                            \
      long gk = g0 + (long)rstr*((ktv)*32 + row);                                      \
      const unsigned short* src = Kg + gk*128 + ((ll ^ (row & 7)) * 8);                \
      gload_lds16((const void*)src, (void*)(Kb + rbase*256));                          \
    }                                                                                  \
    int rank_base = rb0 + (ktv)*32;                                                    \
    _Pragma("unroll")                                                                  \
    for (int i_=0;i_<2;++i_){                                                          \
      int li = i_*256 + tid;                                                           \
      int d_  = li >> 2;                                                               \
      int s_  = li & 3;                                                                \
      int g_  = (s_ - (d_>>1)) & 3;                                                    \
      const unsigned short* src = VTb + (long)d_*NC + rank_base + g_*8;                \
      gload_lds16((const void*)src, (void*)(Vb + i_*4096 + wid*1024));                 \
    }                                                                                  \
  }

  // prologue: stage first two tiles into slots 0,1 (n32 >= 2 always)
  STAGE(t032, 0);
  STAGE(t032 + 1, 1);

  for (int it=0; it<n32; ++it){
    const int kt = t032 + it;
    // drain OWN batch it before the barrier; allow the single newer batch to stay in flight.
    // lgkmcnt(0): all our LDS reads (previous compute) must be SERVICED before we signal the
    // barrier — closes the ds_read-vs-DMA-overwrite race on ring slot (it-1)%3.
    if (it + 1 < n32){
      asm volatile("s_waitcnt vmcnt(4) lgkmcnt(0)" ::: "memory");
    } else {
      asm volatile("s_waitcnt vmcnt(0) lgkmcnt(0)" ::: "memory");
    }
    __builtin_amdgcn_s_barrier();
    __builtin_amdgcn_sched_barrier(0);

    if (kt*32 <= qrow_w + 31){
      unsigned char* Kc = smem + (it % 3)*8192;
      unsigned char* Vc = smem + 24576 + (it % 3)*8192;
      // S^T = K Q^T : s[mt][nt] holds S[q=mt*16+ll][kv=kt*32+nt*16+hi*4+rr]
      f32x4 s[2][2];
      #pragma unroll
      for (int mt=0;mt<2;++mt){
        #pragma unroll
        for (int nt=0;nt<2;++nt) s[mt][nt]=splat4(0.f);
      }
      __builtin_amdgcn_s_setprio(1);
      #pragma unroll
      for (int nt=0;nt<2;++nt){
        int krow = nt*16 + ll;
        #pragma unroll
        for (int ks=0;ks<4;++ks){
          int chunk = (ks*4 + hi) ^ (krow & 7);
          bf16x8 bk = ld_bf8(Kc + krow*256 + chunk*16);
          s[0][nt] = MFMA(bk, aq[0][ks], s[0][nt]);
          s[1][nt] = MFMA(bk, aq[1][ks], s[1][nt]);
        }
      }
      __builtin_amdgcn_s_setprio(0);
      if (kt*32 + 31 > qrow_w){          // diagonal tiles: causal mask
        #pragma unroll
        for (int mt=0;mt<2;++mt){
          int qrow = qrow_w + mt*16 + ll;
          #pragma unroll
          for (int nt=0;nt<2;++nt){
            int kvcol = kt*32 + nt*16 + hi*4;
            #pragma unroll
            for (int rr=0;rr<4;++rr) if (kvcol + rr > qrow) s[mt][nt][rr] = -1e30f;
          }
        }
      }
      // online softmax (base-2), defer-max thr 8; lane ll owns q = mt*16+ll.
      // lrun kept lane-partial (reduced in epilogue).
      #pragma unroll
      for (int mt=0;mt<2;++mt){
        f32x4 t4 = vmax4(s[mt][0], s[mt][1]);
        float mloc = fmaxf(fmaxf(t4[0],t4[1]), fmaxf(t4[2],t4[3]));
        mloc = fmaxf(mloc, __shfl_xor(mloc, 16, 64));
        mloc = fmaxf(mloc, __shfl_xor(mloc, 32, 64));
        bool upd = __any(mloc > mrun[mt] + 8.0f);
        if (upd){
          float mnew = fmaxf(mrun[mt], mloc);
          float sc = EXP2F(mrun[mt] - mnew);
          mrun[mt] = mnew;
          lrun[mt] *= sc;
          f32x4 scv;
          #pragma unroll
          for (int rr=0;rr<4;++rr) scv[rr] = __shfl(sc, hi*4 + rr, 64);
          #pragma unroll
          for (int dt=0;dt<8;++dt) o[mt][dt] = o[mt][dt]*scv;
        }
        f32x4 tsum = splat4(0.f);
        #pragma unroll
        for (int nt=0;nt<2;++nt){
          #pragma unroll
          for (int rr=0;rr<4;++rr) s[mt][nt][rr] = EXP2F(s[mt][nt][rr] - mrun[mt]);
          tsum += s[mt][nt];
        }
        lrun[mt] += (tsum[0]+tsum[1]) + (tsum[2]+tsum[3]);
      }
      // P pack: LANE-LOCAL (kv-permuted V^T makes B-slot (hi,e) = kv (e>=4)*16+hi*4+(e&3))
      bf16x8 pa[2];
      #pragma unroll
      for (int mt=0;mt<2;++mt){
        u16x8 up;
        #pragma unroll
        for (int rr=0;rr<4;++rr){
          up[rr]   = f2bf(s[mt][0][rr]);
          up[4+rr] = f2bf(s[mt][1][rr]);
        }
        pa[mt] = __builtin_bit_cast(bf16x8, up);
      }
      // O += P V  (V^T rows d in LDS, conflict-free swizzled b128 reads)
      __builtin_amdgcn_s_setprio(1);
      #pragma unroll
      for (int dt=0;dt<8;++dt){
        int d = dt*16 + ll;
        int sw = (hi + (d>>1)) & 3;
        bf16x8 bv = ld_bf8(Vc + d*64 + sw*16);
        o[0][dt] = MFMA(pa[0], bv, o[0][dt]);
        o[1][dt] = MFMA(pa[1], bv, o[1][dt]);
      }
      __builtin_amdgcn_s_setprio(0);
    }

    // stage tile it+2 AFTER compute: all waves passed barrier #it, so slot (it+2)%3=(it-1)%3 is free
    if (it + 2 < n32){
      STAGE(kt + 2, (it + 2) % 3);
    }
  }
#undef STAGE

  // epilogue: reduce lane-partial lrun across hi groups, write normalized O (bf16) + base-2 lse
  unsigned short* op = OP + (long)P*16384;
  float* lp = LP + (long)P*128;
  #pragma unroll
  for (int mt=0;mt<2;++mt){
    float l = lrun[mt];
    l += __shfl_xor(l, 16, 64);
    l += __shfl_xor(l, 32, 64);
    float invs = 1.f / l;
    f32x4 iv;
    #pragma unroll
    for (int rr=0;rr<4;++rr) iv[rr] = __shfl(invs, hi*4 + rr, 64);
    #pragma unroll
    for (int dt=0;dt<8;++dt){
      f32x4 res = o[mt][dt]*iv;
      #pragma unroll
      for (int rr=0;rr<4;++rr){
        int qloc = wid*32 + mt*16 + hi*4 + rr;
        op[qloc*128 + dt*16 + ll] = f2bf(res[rr]);
      }
    }
    float lse = mrun[mt] + LOG2F(l);
    if (lane < 16){
      lp[wid*32 + mt*16 + lane] = lse;
    }
  }
}

// ---------------- combine partials (softmax over base-2 lse) + Wo GEMM
__global__ __launch_bounds__(256) void k_comb(
    const unsigned short* __restrict__ OP, const float* __restrict__ LP,
    const unsigned short* __restrict__ wT, float* __restrict__ out){
  const int tid=threadIdx.x, lane=tid&63, wid=tid>>6, ll=lane&15, hi=lane>>4;
  const long row0 = (long)blockIdx.x*128 + wid*32;
  bf16x8 a[2][4];
  #pragma unroll
  for (int mt=0;mt<2;++mt){
    int g = (int)(row0 + mt*16 + ll);
    int bb = g >> 13;
    int posn = g & 8191;
    bool bv[3]; int pbase[3]; int ql[3]; int bn[3];
    {
      int sid = bb*4 + (posn >> 11);
      int qrow = posn & 2047;
      int qb = qrow >> 7;
      bv[0]=true; ql[0]=qrow & 127; bn[0]=(qb<6)?1:(qb<12)?2:3; pbase[0]=sid*30 + CB[qb];
    }
    if ((posn & 1) == 0){
      int p1 = posn >> 1;
      int sid = 16 + bb*2 + (p1 >> 11);
      int qrow = p1 & 2047;
      int qb = qrow >> 7;
      bv[1]=true; ql[1]=qrow & 127; bn[1]=(qb<6)?1:(qb<12)?2:3; pbase[1]=sid*30 + CB[qb];
    } else { bv[1]=false; ql[1]=0; bn[1]=0; pbase[1]=0; }
    if ((posn & 3) == 0){
      int p2 = posn >> 2;
      int sid = 24 + bb;
      int qb = p2 >> 7;
      bv[2]=true; ql[2]=p2 & 127; bn[2]=(qb<6)?1:(qb<12)?2:3; pbase[2]=sid*30 + CB[qb];
    } else { bv[2]=false; ql[2]=0; bn[2]=0; pbase[2]=0; }

    float Lx[3][3];
    #pragma unroll
    for (int b=0;b<3;++b){
      #pragma unroll
      for (int c=0;c<3;++c){
        bool v = bv[b] && (c < bn[b]);
        Lx[b][c] = v ? LP[(pbase[b]+c)*128 + ql[b]] : -1e30f;
      }
    }
    float mx = -1e30f;
    #pragma unroll
    for (int b=0;b<3;++b){
      #pragma unroll
      for (int c=0;c<3;++c) mx = fmaxf(mx, Lx[b][c]);
    }
    float W[3][3]; float wsum = 0.f;
    #pragma unroll
    for (int b=0;b<3;++b){
      #pragma unroll
      for (int c=0;c<3;++c){
        bool v = bv[b] && (c < bn[b]);
        W[b][c] = v ? EXP2F(Lx[b][c] - mx) : 0.f;
        wsum += W[b][c];
      }
    }
    float inv = 1.f / wsum;

    float y[4][8];
    #pragma unroll
    for (int ks=0;ks<4;++ks){
      #pragma unroll
      for (int jj=0;jj<8;++jj) y[ks][jj]=0.f;
    }
    #pragma unroll
    for (int b=0;b<3;++b){
      #pragma unroll
      for (int c=0;c<3;++c){
        if (bv[b] && (c < bn[b])){
          const unsigned short* p = OP + (long)(pbase[b]+c)*16384 + ql[b]*128 + hi*8;
          float wgt = W[b][c];
          #pragma unroll
          for (int ks=0;ks<4;++ks){
            u16x8 u = *(const u16x8*)(const void*)(p + ks*32);
            #pragma unroll
            for (int jj=0;jj<8;++jj) y[ks][jj] += wgt * bf2f(u[jj]);
          }
        }
      }
    }
    #pragma unroll
    for (int ks=0;ks<4;++ks){
      u16x8 u;
      #pragma unroll
      for (int jj=0;jj<8;++jj) u[jj] = f2bf(y[ks][jj]*inv);
      a[mt][ks] = __builtin_bit_cast(bf16x8, u);
    }
  }
  const unsigned short* wp = wT + 3*16384 + ll*128 + hi*8;
  #pragma unroll
  for (int nt=0;nt<8;++nt){
    f32x4 acc0=splat4(0.f), acc1=splat4(0.f);
    #pragma unroll
    for (int ks=0;ks<4;++ks){
      bf16x8 b = ld_bf8(wp + nt*2048 + ks*32);
      acc0 = MFMA(a[0][ks], b, acc0);
      acc1 = MFMA(a[1][ks], b, acc1);
    }
    #pragma unroll
    for (int rr=0;rr<4;++rr){
      out[(row0 + hi*4 + rr)*128 + nt*16 + ll] = acc0[rr];
      out[(row0 + 16 + hi*4 + rr)*128 + nt*16 + ll] = acc1[rr];
    }
  }
}

extern "C" void kernel_launch(void* const* d_in, const int* in_sizes, int n_in,
                              void* d_out, int out_size, void* d_ws, size_t ws_size,
                              hipStream_t stream){
  const float* x  = (const float*)d_in[0];
  const float* Wq = (const float*)d_in[1];
  const float* Wk = (const float*)d_in[2];
  const float* Wv = (const float*)d_in[3];
  const float* Wo = (const float*)d_in[4];
  char* ws = (char*)d_ws;
  unsigned short* wT  = (unsigned short*)(ws);                 // 131072 B
  unsigned short* Q   = (unsigned short*)(ws + 131072);        // 8388608 B
  unsigned short* K   = (unsigned short*)(ws + 8519680);       // 8388608 B
  unsigned short* VT0 = (unsigned short*)(ws + 16908288);      // 8388608 B  [128][32768] (kv-permuted)
  unsigned short* VT1 = (unsigned short*)(ws + 25296896);      // 4194304 B  [128][16384] (kv-permuted)
  unsigned short* VT2 = (unsigned short*)(ws + 29491200);      // 2097152 B  [128][8192]  (kv-permuted)
  unsigned short* OP  = (unsigned short*)(ws + 31588352);      // 27525120 B
  float* LP           = (float*)(ws + 59113472);               // 430080 B -> end 59543552
  k_prep<<<256, 256, 0, stream>>>(Wq, Wk, Wv, Wo, wT);
  k_qkv <<<256, 256, 0, stream>>>(x, wT, Q, K, VT0, VT1, VT2);
  k_attn<<<840, 256, 0, stream>>>(Q, K, VT0, VT1, VT2, OP, LP);
  k_comb<<<256, 256, 0, stream>>>(OP, LP, wT, (float*)d_out);
}

// Round 2
// 113.285 us; speedup vs baseline: 1.0016x; 1.0016x over previous
//
#include <hip/hip_runtime.h>
#include <hip/hip_bf16.h>

typedef __attribute__((ext_vector_type(8))) __bf16 bf16x8;
typedef __attribute__((ext_vector_type(4))) float f32x4;
typedef __attribute__((ext_vector_type(8))) unsigned short u16x8;

#define DEVI __device__ __forceinline__
#define MFMA(a,b,c) __builtin_amdgcn_mfma_f32_16x16x32_bf16((a),(b),(c),0,0,0)
#define EXP2F(x) __builtin_exp2f(x)
#define LOG2F(x) __builtin_log2f(x)

DEVI unsigned short f2bf(float f){ __bf16 h = (__bf16)f; return __builtin_bit_cast(unsigned short, h); }
DEVI float bf2f(unsigned short u){ unsigned int x = ((unsigned int)u) << 16; return __builtin_bit_cast(float, x); }
DEVI bf16x8 ld_bf8(const void* p){ u16x8 u = *(const u16x8*)p; return __builtin_bit_cast(bf16x8, u); }
DEVI f32x4 splat4(float x){ f32x4 v = {x,x,x,x}; return v; }
DEVI f32x4 vmax4(f32x4 a, f32x4 b){
  f32x4 r;
  #pragma unroll
  for (int i=0;i<4;++i) r[i]=fmaxf(a[i],b[i]);
  return r;
}
DEVI void gload_lds16(const void* g, void* l){
  void* g2 = const_cast<void*>(g);
  __builtin_amdgcn_global_load_lds((__attribute__((address_space(1))) void*)g2,
                                   (__attribute__((address_space(3))) void*)l, 16, 0, 0);
}

// schedule table: 30 chunks per segment, heavy-first. qb | t0<<8 | ntiles<<16 | slot<<24 (64-row tile units)
__device__ const unsigned int SCHED[30] = {
  0x100C000Bu, 0x110C0C0Bu, 0x050C0005u, 0x1C0B0A0Fu, 0x1D0B150Fu,
  0x0E0B000Au, 0x0F0B0B0Au, 0x1B0A000Fu, 0x180A000Eu, 0x190A0A0Eu,
  0x1A0A140Eu, 0x170A120Du, 0x0C0A0009u, 0x0D0A0A09u, 0x040A0004u,
  0x1509000Du, 0x1609090Du, 0x1309080Cu, 0x1409110Cu, 0x0A090008u,
  0x0B090908u, 0x1208000Cu, 0x08080007u, 0x09080807u, 0x03080003u,
  0x06070006u, 0x07070706u, 0x02060002u, 0x01040001u, 0x00020000u
};
// canonical chunk-base per qb (prefix of nchunks {1x6, 2x6, 3x4})
__device__ const int CB[16] = {0,1,2,3,4,5,6,8,10,12,14,16,18,21,24,27};

// ---------------- prep: transpose weights to [mat][col][k] bf16; fold 1/(sqrt(c)*ln2) into Wq (base-2 softmax)
__global__ __launch_bounds__(256) void k_prep(const float* __restrict__ Wq, const float* __restrict__ Wk,
                                              const float* __restrict__ Wv, const float* __restrict__ Wo,
                                              unsigned short* __restrict__ wT){
  int i = blockIdx.x*256 + threadIdx.x;              // 0..65535
  int mat = i >> 14, col = (i >> 7) & 127, k = i & 127;
  const float* W = (mat==0)?Wq:(mat==1)?Wk:(mat==2)?Wv:Wo;
  float v = W[k*128 + col];
  if (mat == 0) v *= 0.12754245006257017f;           // 1/(sqrt(128)*ln2)
  wT[i] = f2bf(v);
}

// ---------------- QKV projection + in-kernel V transpose to branch-local, kv-permuted V^T arrays.
// Within each 32-rank block, rank kv is stored at position p = ((kv&15)>>2)*8 + ((kv>>4)&1)*4 + (kv&3),
// so the PV B-operand k-slot (hi,e) holds kv = (e>=4)*16 + hi*4 + (e&3)  ->  P pack is lane-local.
__global__ __launch_bounds__(256) void k_qkv(const float* __restrict__ x, const unsigned short* __restrict__ wT,
                                             unsigned short* __restrict__ Qo, unsigned short* __restrict__ Ko,
                                             unsigned short* __restrict__ VT0, unsigned short* __restrict__ VT1,
                                             unsigned short* __restrict__ VT2){
  __shared__ unsigned short Tl[128*130];             // [token 0..127][d 0..127], row stride 130
  const int tid=threadIdx.x, lane=tid&63, wid=tid>>6, ll=lane&15, hi=lane>>4;
  const int row0g = blockIdx.x*128;
  const long row0 = (long)row0g + wid*32;
  bf16x8 a[2][4];
  #pragma unroll
  for (int mt=0;mt<2;++mt){
    const float* xr = x + (row0 + mt*16 + ll)*128 + hi*8;
    #pragma unroll
    for (int ks=0;ks<4;++ks){
      f32x4 f0 = *(const f32x4*)(const void*)(xr + ks*32);
      f32x4 f1 = *(const f32x4*)(const void*)(xr + ks*32 + 4);
      u16x8 u;
      #pragma unroll
      for (int j=0;j<4;++j){ u[j]=f2bf(f0[j]); u[j+4]=f2bf(f1[j]); }
      a[mt][ks] = __builtin_bit_cast(bf16x8, u);
    }
  }
  #pragma unroll
  for (int m3=0;m3<3;++m3){
    const unsigned short* wp = wT + m3*16384 + ll*128 + hi*8;
    #pragma unroll
    for (int nt=0;nt<8;++nt){
      f32x4 acc0=splat4(0.f), acc1=splat4(0.f);
      #pragma unroll
      for (int ks=0;ks<4;++ks){
        bf16x8 b = ld_bf8(wp + nt*2048 + ks*32);
        acc0 = MFMA(a[0][ks], b, acc0);
        acc1 = MFMA(a[1][ks], b, acc1);
      }
      if (m3 < 2){
        unsigned short* outp = (m3==0)?Qo:Ko;
        #pragma unroll
        for (int r=0;r<4;++r){
          outp[(row0 + hi*4 + r)*128 + nt*16 + ll]      = f2bf(acc0[r]);
          outp[(row0 + 16 + hi*4 + r)*128 + nt*16 + ll] = f2bf(acc1[r]);
        }
      } else {
        #pragma unroll
        for (int r=0;r<4;++r){
          Tl[(wid*32 + hi*4 + r)*130 + nt*16 + ll]      = f2bf(acc0[r]);
          Tl[(wid*32 + 16 + hi*4 + r)*130 + nt*16 + ll] = f2bf(acc1[r]);
        }
      }
    }
  }
  __syncthreads();
  // write-out V^T rows, kv-permuted within 32-rank blocks (rank pair 2*lane,2*lane+1 stays adjacent:
  // for even rank r&3 in {0,2}, p(kv+1)=p(kv)+1)
  int tk = 2*lane;
  int pp0 = (tk>>5)*32 + ((tk>>4)&1)*4 + ((tk&15)>>2)*8 + (tk&3);
  #pragma unroll 4
  for (int p=0;p<32;++p){
    int d = wid*32 + p;
    unsigned int w0 = (unsigned int)Tl[(2*lane)*130 + d] | ((unsigned int)Tl[(2*lane+1)*130 + d] << 16);
    *(unsigned int*)(VT0 + (long)d*32768 + row0g + pp0) = w0;
    if (lane < 32){
      unsigned int w1 = (unsigned int)Tl[(4*lane)*130 + d] | ((unsigned int)Tl[(4*lane+2)*130 + d] << 16);
      *(unsigned int*)(VT1 + (long)d*16384 + (row0g>>1) + pp0) = w1;
    }
    if (lane < 16){
      unsigned int w2 = (unsigned int)Tl[(8*lane)*130 + d] | ((unsigned int)Tl[(8*lane+4)*130 + d] << 16);
      *(unsigned int*)(VT2 + (long)d*8192 + (row0g>>2) + pp0) = w2;
    }
  }
}

// ---------------- flash attention: KV tile 32, DMA-staged K+V, ring-3 buffers.
// Per iteration: counted vmcnt + FULL lgkm drain -> s_barrier -> STAGE(it+2) -> compute(it).
// Race-free: lgkmcnt(0) before the barrier guarantees every wave's slot-((it-1)%3) LDS reads are SERVICED
// before it signals barrier #it; STAGE(it+2) overwrites exactly that slot, and issues only after the
// barrier releases. Issuing the STAGE BEFORE compute (not after) adds ~one compute phase of prefetch
// lead (~1300+ cy), covering HBM-miss latency (~900 cy) that the old placement left exposed.
// XCD-locality remap: XCD (b&7) owns 3 whole segments + half of one br=2 segment (tile balance +-2.5%),
// shrinking each XCD's concurrent K/V working set from ~23MB (all 28 segments) to ~4-8MB.
__global__ __launch_bounds__(256,3) void k_attn(
    const unsigned short* __restrict__ Qg, const unsigned short* __restrict__ Kg,
    const unsigned short* __restrict__ VT0, const unsigned short* __restrict__ VT1,
    const unsigned short* __restrict__ VT2,
    unsigned short* __restrict__ OP, float* __restrict__ LP){
  __shared__ unsigned char smem[49152];
  // K ring: 3 x 8KB at smem + s*8192 ; V ring: 3 x 8KB at smem + 24576 + s*8192

  const int tid=threadIdx.x, lane=tid&63, wid=tid>>6, ll=lane&15, hi=lane>>4;

  // ---- XCD-locality block remap: XCD x = b&7 (HW round-robin), slot i = b>>3 (0..104).
  // XCD x runs sids {3x,3x+1,3x+2} fully + half of sid 24+(x>>1) (x even: heavy r0-14, odd: light r15-29).
  // Slot order merges the 3.5 lists by descending chunk size (heavy-first, light tail).
  int x = blockIdx.x & 7;
  int i = blockIdx.x >> 3;
  int sid, r;
  if (i < 60){
    r = i >> 2; int k = i & 3;
    if (k < 3){ sid = 3*x + k; }
    else { sid = 24 + (x >> 1); if (x & 1) r += 15; }
  } else {
    int t = i - 60; r = 15 + t/3; sid = 3*x + t%3;
  }
  unsigned int e = SCHED[r];
  int qb   = (int)(e & 255u);
  int t032 = (int)((e >> 8) & 255u) * 2;
  int n32  = (int)((e >> 16) & 255u) * 2;
  int slot = (int)(e >> 24);
  int br, bb, seg;
  if (sid < 16){ br=0; bb=sid>>2; seg=sid&3; }
  else if (sid < 24){ br=1; bb=(sid-16)>>1; seg=(sid-16)&1; }
  else { br=2; bb=sid-24; seg=0; }
  const int rstr = 1 << br;
  const long g0 = (long)bb*8192 + (long)seg*(2048 << br);
  const int P = sid*30 + slot;
  const unsigned short* VTb = (br==0)?VT0:(br==1)?VT1:VT2;
  const int NC = 32768 >> br;
  const int rb0 = (int)(g0 >> br);

  const int qrow_w = qb*128 + wid*32;

  bf16x8 aq[2][4];
  #pragma unroll
  for (int mt=0;mt<2;++mt){
    long gq = g0 + (long)rstr*(qrow_w + mt*16 + ll);
    const unsigned short* qp = Qg + gq*128 + hi*8;
    #pragma unroll
    for (int ks=0;ks<4;++ks) aq[mt][ks] = ld_bf8(qp + ks*32);
  }

  f32x4 o[2][8];
  #pragma unroll
  for (int mt=0;mt<2;++mt){
    #pragma unroll
    for (int dt=0;dt<8;++dt) o[mt][dt]=splat4(0.f);
  }
  float mrun[2], lrun[2];
  mrun[0]=mrun[1]=-1e30f; lrun[0]=lrun[1]=0.f;

  // stage tile (32 rows) kt into ring slot b: 2 K-gloads + 2 V-gloads per wave (4 total)
#define STAGE(ktv, bslot)                                                              \
  {                                                                                    \
    unsigned char* Kb = smem + (bslot)*8192;                                           \
    unsigned char* Vb = smem + 24576 + (bslot)*8192;                                   \
    _Pragma("unroll")                                                                  \
    for (int i_=0;i_<2;++i_){                                                          \
      int rbase = wid*8 + i_*4;                                                        \
      int row = rbase + hi;                                                            \
      long gk = g0 + (long)rstr*((ktv)*32 + row);                                      \
      const unsigned short* src = Kg + gk*128 + ((ll ^ (row & 7)) * 8);                \
      gload_lds16((const void*)src, (void*)(Kb + rbase*256));                          \
    }                                                                                  \
    int rank_base = rb0 + (ktv)*32;                                                    \
    _Pragma("unroll")                                                                  \
    for (int i_=0;i_<2;++i_){                                                          \
      int li = i_*256 + tid;                                                           \
      int d_  = li >> 2;                                                               \
      int s_  = li & 3;                                                                \
      int g_  = (s_ - (d_>>1)) & 3;                                                    \
      const unsigned short* src = VTb + (long)d_*NC + rank_base + g_*8;                \
      gload_lds16((const void*)src, (void*)(Vb + i_*4096 + wid*1024));                 \
    }                                                                                  \
  }

  // prologue: stage first two tiles into slots 0,1 (n32 >= 2 always)
  STAGE(t032, 0);
  STAGE(t032 + 1, 1);

  for (int it=0; it<n32; ++it){
    const int kt = t032 + it;
    // drain OWN batch it before the barrier; allow the single newer batch to stay in flight.
    // lgkmcnt(0): all our LDS reads (previous compute) must be SERVICED before we signal the
    // barrier — closes the ds_read-vs-DMA-overwrite race on ring slot (it-1)%3.
    if (it + 1 < n32){
      asm volatile("s_waitcnt vmcnt(4) lgkmcnt(0)" ::: "memory");
    } else {
      asm volatile("s_waitcnt vmcnt(0) lgkmcnt(0)" ::: "memory");
    }
    __builtin_amdgcn_s_barrier();
    __builtin_amdgcn_sched_barrier(0);

    // stage tile it+2 EARLY (right after the barrier): slot (it+2)%3 = (it-1)%3 is free the moment
    // all waves pass barrier #it (lgkm drained). Issuing before compute adds a full compute phase
    // of DMA lead so even HBM misses are covered by the top-of-loop vmcnt.
    if (it + 2 < n32){
      STAGE(kt + 2, (it + 2) % 3);
    }

    if (kt*32 <= qrow_w + 31){
      unsigned char* Kc = smem + (it % 3)*8192;
      unsigned char* Vc = smem + 24576 + (it % 3)*8192;
      // S^T = K Q^T : s[mt][nt] holds S[q=mt*16+ll][kv=kt*32+nt*16+hi*4+rr]
      f32x4 s[2][2];
      #pragma unroll
      for (int mt=0;mt<2;++mt){
        #pragma unroll
        for (int nt=0;nt<2;++nt) s[mt][nt]=splat4(0.f);
      }
      __builtin_amdgcn_s_setprio(1);
      #pragma unroll
      for (int nt=0;nt<2;++nt){
        int krow = nt*16 + ll;
        #pragma unroll
        for (int ks=0;ks<4;++ks){
          int chunk = (ks*4 + hi) ^ (krow & 7);
          bf16x8 bk = ld_bf8(Kc + krow*256 + chunk*16);
          s[0][nt] = MFMA(bk, aq[0][ks], s[0][nt]);
          s[1][nt] = MFMA(bk, aq[1][ks], s[1][nt]);
        }
      }
      __builtin_amdgcn_s_setprio(0);
      if (kt*32 + 31 > qrow_w){          // diagonal tiles: causal mask
        #pragma unroll
        for (int mt=0;mt<2;++mt){
          int qrow = qrow_w + mt*16 + ll;
          #pragma unroll
          for (int nt=0;nt<2;++nt){
            int kvcol = kt*32 + nt*16 + hi*4;
            #pragma unroll
            for (int rr=0;rr<4;++rr) if (kvcol + rr > qrow) s[mt][nt][rr] = -1e30f;
          }
        }
      }
      // online softmax (base-2), defer-max thr 8; lane ll owns q = mt*16+ll.
      // lrun kept lane-partial (reduced in epilogue).
      #pragma unroll
      for (int mt=0;mt<2;++mt){
        f32x4 t4 = vmax4(s[mt][0], s[mt][1]);
        float mloc = fmaxf(fmaxf(t4[0],t4[1]), fmaxf(t4[2],t4[3]));
        mloc = fmaxf(mloc, __shfl_xor(mloc, 16, 64));
        mloc = fmaxf(mloc, __shfl_xor(mloc, 32, 64));
        bool upd = __any(mloc > mrun[mt] + 8.0f);
        if (upd){
          float mnew = fmaxf(mrun[mt], mloc);
          float sc = EXP2F(mrun[mt] - mnew);
          mrun[mt] = mnew;
          lrun[mt] *= sc;
          f32x4 scv;
          #pragma unroll
          for (int rr=0;rr<4;++rr) scv[rr] = __shfl(sc, hi*4 + rr, 64);
          #pragma unroll
          for (int dt=0;dt<8;++dt) o[mt][dt] = o[mt][dt]*scv;
        }
        f32x4 tsum = splat4(0.f);
        #pragma unroll
        for (int nt=0;nt<2;++nt){
          #pragma unroll
          for (int rr=0;rr<4;++rr) s[mt][nt][rr] = EXP2F(s[mt][nt][rr] - mrun[mt]);
          tsum += s[mt][nt];
        }
        lrun[mt] += (tsum[0]+tsum[1]) + (tsum[2]+tsum[3]);
      }
      // P pack: LANE-LOCAL (kv-permuted V^T makes B-slot (hi,e) = kv (e>=4)*16+hi*4+(e&3))
      bf16x8 pa[2];
      #pragma unroll
      for (int mt=0;mt<2;++mt){
        u16x8 up;
        #pragma unroll
        for (int rr=0;rr<4;++rr){
          up[rr]   = f2bf(s[mt][0][rr]);
          up[4+rr] = f2bf(s[mt][1][rr]);
        }
        pa[mt] = __builtin_bit_cast(bf16x8, up);
      }
      // O += P V  (V^T rows d in LDS, conflict-free swizzled b128 reads)
      __builtin_amdgcn_s_setprio(1);
      #pragma unroll
      for (int dt=0;dt<8;++dt){
        int d = dt*16 + ll;
        int sw = (hi + (d>>1)) & 3;
        bf16x8 bv = ld_bf8(Vc + d*64 + sw*16);
        o[0][dt] = MFMA(pa[0], bv, o[0][dt]);
        o[1][dt] = MFMA(pa[1], bv, o[1][dt]);
      }
      __builtin_amdgcn_s_setprio(0);
    }
  }
#undef STAGE

  // epilogue: reduce lane-partial lrun across hi groups, write normalized O (bf16) + base-2 lse
  unsigned short* op = OP + (long)P*16384;
  float* lp = LP + (long)P*128;
  #pragma unroll
  for (int mt=0;mt<2;++mt){
    float l = lrun[mt];
    l += __shfl_xor(l, 16, 64);
    l += __shfl_xor(l, 32, 64);
    float invs = 1.f / l;
    f32x4 iv;
    #pragma unroll
    for (int rr=0;rr<4;++rr) iv[rr] = __shfl(invs, hi*4 + rr, 64);
    #pragma unroll
    for (int dt=0;dt<8;++dt){
      f32x4 res = o[mt][dt]*iv;
      #pragma unroll
      for (int rr=0;rr<4;++rr){
        int qloc = wid*32 + mt*16 + hi*4 + rr;
        op[qloc*128 + dt*16 + ll] = f2bf(res[rr]);
      }
    }
    float lse = mrun[mt] + LOG2F(l);
    if (lane < 16){
      lp[wid*32 + mt*16 + lane] = lse;
    }
  }
}

// ---------------- combine partials (softmax over base-2 lse) + Wo GEMM
__global__ __launch_bounds__(256) void k_comb(
    const unsigned short* __restrict__ OP, const float* __restrict__ LP,
    const unsigned short* __restrict__ wT, float* __restrict__ out){
  const int tid=threadIdx.x, lane=tid&63, wid=tid>>6, ll=lane&15, hi=lane>>4;
  const long row0 = (long)blockIdx.x*128 + wid*32;
  bf16x8 a[2][4];
  #pragma unroll
  for (int mt=0;mt<2;++mt){
    int g = (int)(row0 + mt*16 + ll);
    int bb = g >> 13;
    int posn = g & 8191;
    bool bv[3]; int pbase[3]; int ql[3]; int bn[3];
    {
      int sid = bb*4 + (posn >> 11);
      int qrow = posn & 2047;
      int qb = qrow >> 7;
      bv[0]=true; ql[0]=qrow & 127; bn[0]=(qb<6)?1:(qb<12)?2:3; pbase[0]=sid*30 + CB[qb];
    }
    if ((posn & 1) == 0){
      int p1 = posn >> 1;
      int sid = 16 + bb*2 + (p1 >> 11);
      int qrow = p1 & 2047;
      int qb = qrow >> 7;
      bv[1]=true; ql[1]=qrow & 127; bn[1]=(qb<6)?1:(qb<12)?2:3; pbase[1]=sid*30 + CB[qb];
    } else { bv[1]=false; ql[1]=0; bn[1]=0; pbase[1]=0; }
    if ((posn & 3) == 0){
      int p2 = posn >> 2;
      int sid = 24 + bb;
      int qb = p2 >> 7;
      bv[2]=true; ql[2]=p2 & 127; bn[2]=(qb<6)?1:(qb<12)?2:3; pbase[2]=sid*30 + CB[qb];
    } else { bv[2]=false; ql[2]=0; bn[2]=0; pbase[2]=0; }

    float Lx[3][3];
    #pragma unroll
    for (int b=0;b<3;++b){
      #pragma unroll
      for (int c=0;c<3;++c){
        bool v = bv[b] && (c < bn[b]);
        Lx[b][c] = v ? LP[(pbase[b]+c)*128 + ql[b]] : -1e30f;
      }
    }
    float mx = -1e30f;
    #pragma unroll
    for (int b=0;b<3;++b){
      #pragma unroll
      for (int c=0;c<3;++c) mx = fmaxf(mx, Lx[b][c]);
    }
    float W[3][3]; float wsum = 0.f;
    #pragma unroll
    for (int b=0;b<3;++b){
      #pragma unroll
      for (int c=0;c<3;++c){
        bool v = bv[b] && (c < bn[b]);
        W[b][c] = v ? EXP2F(Lx[b][c] - mx) : 0.f;
        wsum += W[b][c];
      }
    }
    float inv = 1.f / wsum;

    float y[4][8];
    #pragma unroll
    for (int ks=0;ks<4;++ks){
      #pragma unroll
      for (int jj=0;jj<8;++jj) y[ks][jj]=0.f;
    }
    #pragma unroll
    for (int b=0;b<3;++b){
      #pragma unroll
      for (int c=0;c<3;++c){
        if (bv[b] && (c < bn[b])){
          const unsigned short* p = OP + (long)(pbase[b]+c)*16384 + ql[b]*128 + hi*8;
          float wgt = W[b][c];
          #pragma unroll
          for (int ks=0;ks<4;++ks){
            u16x8 u = *(const u16x8*)(const void*)(p + ks*32);
            #pragma unroll
            for (int jj=0;jj<8;++jj) y[ks][jj] += wgt * bf2f(u[jj]);
          }
        }
      }
    }
    #pragma unroll
    for (int ks=0;ks<4;++ks){
      u16x8 u;
      #pragma unroll
      for (int jj=0;jj<8;++jj) u[jj] = f2bf(y[ks][jj]*inv);
      a[mt][ks] = __builtin_bit_cast(bf16x8, u);
    }
  }
  const unsigned short* wp = wT + 3*16384 + ll*128 + hi*8;
  #pragma unroll
  for (int nt=0;nt<8;++nt){
    f32x4 acc0=splat4(0.f), acc1=splat4(0.f);
    #pragma unroll
    for (int ks=0;ks<4;++ks){
      bf16x8 b = ld_bf8(wp + nt*2048 + ks*32);
      acc0 = MFMA(a[0][ks], b, acc0);
      acc1 = MFMA(a[1][ks], b, acc1);
    }
    #pragma unroll
    for (int rr=0;rr<4;++rr){
      out[(row0 + hi*4 + rr)*128 + nt*16 + ll] = acc0[rr];
      out[(row0 + 16 + hi*4 + rr)*128 + nt*16 + ll] = acc1[rr];
    }
  }
}

extern "C" void kernel_launch(void* const* d_in, const int* in_sizes, int n_in,
                              void* d_out, int out_size, void* d_ws, size_t ws_size,
                              hipStream_t stream){
  const float* x  = (const float*)d_in[0];
  const float* Wq = (const float*)d_in[1];
  const float* Wk = (const float*)d_in[2];
  const float* Wv = (const float*)d_in[3];
  const float* Wo = (const float*)d_in[4];
  char* ws = (char*)d_ws;
  unsigned short* wT  = (unsigned short*)(ws);                 // 131072 B
  unsigned short* Q   = (unsigned short*)(ws + 131072);        // 8388608 B
  unsigned short* K   = (unsigned short*)(ws + 8519680);       // 8388608 B
  unsigned short* VT0 = (unsigned short*)(ws + 16908288);      // 8388608 B  [128][32768] (kv-permuted)
  unsigned short* VT1 = (unsigned short*)(ws + 25296896);      // 4194304 B  [128][16384] (kv-permuted)
  unsigned short* VT2 = (unsigned short*)(ws + 29491200);      // 2097152 B  [128][8192]  (kv-permuted)
  unsigned short* OP  = (unsigned short*)(ws + 31588352);      // 27525120 B
  float* LP           = (float*)(ws + 59113472);               // 430080 B -> end 59543552
  k_prep<<<256, 256, 0, stream>>>(Wq, Wk, Wv, Wo, wT);
  k_qkv <<<256, 256, 0, stream>>>(x, wT, Q, K, VT0, VT1, VT2);
  k_attn<<<840, 256, 0, stream>>>(Q, K, VT0, VT1, VT2, OP, LP);
  k_comb<<<256, 256, 0, stream>>>(OP, LP, wT, (float*)d_out);
}